// Round 4
// baseline (879.165 us; speedup 1.0000x reference)
//
#include <hip/hip_runtime.h>
#include <hip/hip_bf16.h>

// Problem constants
#define BB   128
#define DV   2048
#define SS   196
#define DQ   2048
#define DA   1200
#define DAP  1280      // DA padded to 10*128 MFMA n-tiles
#define GG   4
#define DH   2048
#define NANS 3000
#define NANSP 3072     // 24*128
#define MROWS (BB*SS)  // 25088 = 196 * 128 exactly
#define NT   10        // n-tiles in big GEMM
#define NQ   (DAP + DH)     // 3328 merged q-branch cols = 26*128
#define KS2  16
#define KCH2 (DV/KS2)       // 128

typedef __attribute__((ext_vector_type(8))) short bf16x8;
typedef __attribute__((ext_vector_type(4))) float f32x4;

__device__ __forceinline__ float fast_tanh(float x) {
    float e = __expf(2.0f * x);
    return 1.0f - 2.0f * __builtin_amdgcn_rcpf(e + 1.0f);
}

__device__ __forceinline__ void async_copy16(const void* gsrc, void* ldst) {
    __builtin_amdgcn_global_load_lds(
        (const __attribute__((address_space(1))) void*)gsrc,
        (__attribute__((address_space(3))) void*)ldst, 16, 0, 0);
}

// ---------------------------------------------------------------------------
// prep: cast x_q -> bf16; pad bv (DA->DAP); pad Wa -> [DAP][4]
// ---------------------------------------------------------------------------
__global__ __launch_bounds__(256) void prep(const float* __restrict__ x_q,
                                            const float* __restrict__ bv,
                                            const float* __restrict__ Wa,
                                            __hip_bfloat16* __restrict__ xqb,
                                            float* __restrict__ bvp,
                                            float* __restrict__ wap) {
    int i = blockIdx.x * 256 + threadIdx.x;
    if (i < BB * DQ) xqb[i] = __float2bfloat16(x_q[i]);
    if (i < DAP) bvp[i] = (i < DA) ? bv[i] : 0.f;
    if (i < DAP * GG) {
        int d = i >> 2;
        wap[i] = (d < DA) ? Wa[i] : 0.f;
    }
}

// ---------------------------------------------------------------------------
// K0a: v [B][DV][S] fp32 -> v_t [(b*S+s)][DV] bf16
// ---------------------------------------------------------------------------
__global__ __launch_bounds__(256) void transpose_v(const float* __restrict__ v,
                                                   __hip_bfloat16* __restrict__ vt) {
    __shared__ float tile[128][65];
    const int b  = blockIdx.z;
    const int c0 = blockIdx.x * 128;
    const int s0 = blockIdx.y * 64;
    const int t  = threadIdx.x;
    const int sl = t & 63;
    const int cr = t >> 6;
    const float* src = v + (size_t)b * DV * SS;
    const int sg = s0 + sl;
    const bool sok = sg < SS;
#pragma unroll
    for (int i = 0; i < 32; ++i) {
        int c = cr + i * 4;
        tile[c][sl] = sok ? src[(size_t)(c0 + c) * SS + sg] : 0.f;
    }
    __syncthreads();
    const int cp = (t & 63) * 2;
#pragma unroll
    for (int i = 0; i < 16; ++i) {
        int s = (t >> 6) + i * 4;
        int sgl = s0 + s;
        if (sgl < SS) {
            __hip_bfloat162 h2;
            h2.x = __float2bfloat16(tile[cp][s]);
            h2.y = __float2bfloat16(tile[cp + 1][s]);
            *(__hip_bfloat162*)(vt + ((size_t)b * SS + sgl) * DV + c0 + cp) = h2;
        }
    }
}

// ---------------------------------------------------------------------------
// Generalized weight transpose: src [2048][ldsrc] fp32 -> dst[n][2048] bf16,
// zero-padding cols >= nreal. blockIdx.z: glimpse slab (srcz elems, dstzrows).
// ---------------------------------------------------------------------------
__global__ __launch_bounds__(256) void transpose_nk(
    const float* __restrict__ src, int ldsrc, int nreal,
    __hip_bfloat16* __restrict__ dst, size_t srcz, int dstzrows) {
    src += (size_t)blockIdx.z * srcz;
    dst += (size_t)blockIdx.z * dstzrows * 2048;
    __shared__ float tile[64][65];
    const int n0 = blockIdx.x * 64;
    const int c0 = blockIdx.y * 64;
    const int t  = threadIdx.x;
    const int col  = t & 63;
    const int rowb = t >> 6;
#pragma unroll
    for (int i = 0; i < 16; ++i) {
        int c = rowb + i * 4;
        int n = n0 + col;
        tile[c][col] = (n < nreal) ? src[(size_t)(c0 + c) * ldsrc + n] : 0.f;
    }
    __syncthreads();
#pragma unroll
    for (int i = 0; i < 16; ++i) {
        int nl = rowb + i * 4;
        dst[(size_t)(n0 + nl) * 2048 + c0 + col] = __float2bfloat16(tile[col][nl]);
    }
}

// ---------------------------------------------------------------------------
// Split-K bf16 MFMA partial GEMM for M=128 stages.
// Cp[ks][128][Npad] += A[128][2048](bf16) * Bt[Npad][2048]^T (bf16).
// A via LDS (XOR swizzle), B direct global->reg (L2-resident weights).
// fus=1: A base shifts by glimpse (n0>>9)*2048; lda covers vattb stride.
// ---------------------------------------------------------------------------
__global__ __launch_bounds__(256) void mfma_partial(
    const __hip_bfloat16* __restrict__ A, int lda,
    const __hip_bfloat16* __restrict__ Bt,
    float* __restrict__ Cp, int Npad, int fus) {
    __shared__ __hip_bfloat16 As[128 * 64];
    const int t    = threadIdx.x;
    const int lane = t & 63;
    const int w    = t >> 6;
    const int wm   = w >> 1, wn = w & 1;
    const int n0   = blockIdx.x * 128;
    const int kbase = blockIdx.y * KCH2;
    const __hip_bfloat16* Ae = A + (fus ? ((size_t)(n0 >> 9) * 2048) : 0);

    f32x4 acc[4][4];
#pragma unroll
    for (int i = 0; i < 4; ++i)
#pragma unroll
        for (int j = 0; j < 4; ++j) acc[i][j] = (f32x4){0.f, 0.f, 0.f, 0.f};

    const int srow   = lane >> 3;
    const int schunk = (lane & 7) ^ srow;
    const __hip_bfloat16* aG = Ae + (size_t)(w * 32 + srow) * lda + kbase + schunk * 8;
    __hip_bfloat16* aL = As + (w * 32) * 64;
    const __hip_bfloat16* bG =
        Bt + (size_t)(n0 + wn * 64 + (lane & 15)) * 2048 + kbase + (lane >> 4) * 8;

    for (int kk = 0; kk < KCH2; kk += 64) {
        __syncthreads();
#pragma unroll
        for (int j = 0; j < 4; ++j)
            async_copy16(aG + (size_t)(j * 8) * lda + kk, aL + j * 8 * 64);
        bf16x8 b[2][4];
#pragma unroll
        for (int ks = 0; ks < 2; ++ks)
#pragma unroll
            for (int ni = 0; ni < 4; ++ni)
                b[ks][ni] = *(const bf16x8*)(bG + (size_t)(ni * 16) * 2048 + kk + ks * 32);
        __syncthreads();
#pragma unroll
        for (int ks = 0; ks < 2; ++ks) {
            const int cx = ((ks * 4 + (lane >> 4)) ^ (lane & 7)) * 8;
            bf16x8 a[4];
#pragma unroll
            for (int mi = 0; mi < 4; ++mi)
                a[mi] = *(const bf16x8*)(As + (wm * 64 + mi * 16 + (lane & 15)) * 64 + cx);
#pragma unroll
            for (int mi = 0; mi < 4; ++mi)
#pragma unroll
                for (int ni = 0; ni < 4; ++ni)
                    acc[mi][ni] = __builtin_amdgcn_mfma_f32_16x16x32_bf16(a[mi], b[ks][ni], acc[mi][ni], 0, 0, 0);
        }
    }
    // C/D layout: col=lane&15 (+16*ni), row=(lane>>4)*4+reg (+16*mi, +64*wm)
#pragma unroll
    for (int mi = 0; mi < 4; ++mi)
#pragma unroll
        for (int r = 0; r < 4; ++r) {
            int row = wm * 64 + mi * 16 + ((lane >> 4) << 2) + r;
            float* cp = Cp + ((size_t)blockIdx.y * 128 + row) * Npad + n0 + wn * 64 + (lane & 15);
#pragma unroll
            for (int ni = 0; ni < 4; ++ni) cp[ni * 16] = acc[mi][ni][r];
        }
}

// q-branch epilogue: cols [0,DAP) -> qatt (tanh, pad->0), [DAP,NQ) -> qfus
__global__ __launch_bounds__(256) void epilogue_q(
    const float* __restrict__ Cp,
    const float* __restrict__ bqa, const float* __restrict__ bqf,
    float* __restrict__ qatt, float* __restrict__ qfus) {
    int n = blockIdx.x * 256 + threadIdx.x;
    int m = blockIdx.y;
    if (n >= NQ) return;
    float s = 0.f;
#pragma unroll
    for (int ks = 0; ks < KS2; ++ks)
        s += Cp[((size_t)ks * 128 + m) * NQ + n];
    if (n < DAP) {
        qatt[(size_t)m * DAP + n] = (n < DA) ? fast_tanh(s + bqa[n]) : 0.f;
    } else {
        int j = n - DAP;
        qfus[(size_t)m * DH + j] = fast_tanh(s + bqf[j]);
    }
}

// Generic epilogue: MODE 0: +bias fp32 out (classifier) | MODE 2: MLB -> bf16
template <int MODE>
__global__ __launch_bounds__(256) void gemm_epilogue(
    const float* __restrict__ Cp, int Npad, int Nreal,
    const float* __restrict__ bias, const float* __restrict__ aux,
    void* __restrict__ outv, int ldo) {
    int n = blockIdx.x * 256 + threadIdx.x;
    int m = blockIdx.y;
    if (n >= Npad) return;
    float s = 0.f;
#pragma unroll
    for (int ks = 0; ks < KS2; ++ks)
        s += Cp[((size_t)ks * 128 + m) * Npad + n];
    if (MODE == 0) {
        if (n >= Nreal) return;
        ((float*)outv)[(size_t)m * ldo + n] = s + bias[n];
    } else {
        float xv = fast_tanh(s + bias[n]);
        float o  = fast_tanh(xv * aux[(size_t)m * 2048 + n]);
        ((__hip_bfloat16*)outv)[(size_t)m * ldo + n] = __float2bfloat16(o);
    }
}

// ---------------------------------------------------------------------------
// K1: big MFMA GEMM. A(vt) via LDS (XOR swizzle), B(wvt) direct global->reg
// (L2-resident via XCD swizzle). Fused epilogue -> per-ntile score partials.
// ---------------------------------------------------------------------------
__global__ __launch_bounds__(256) void big_gemm(
    const __hip_bfloat16* __restrict__ vt,
    const __hip_bfloat16* __restrict__ wt,
    const float* __restrict__ bvp,
    const float* __restrict__ qatt,
    const float* __restrict__ wap,
    float* __restrict__ scores_p) {
    __shared__ __hip_bfloat16 As[128 * 64];
    __shared__ float wa_s[128 * 4];
    __shared__ float sc[128 * 4];
    __shared__ float qs[2 * 128];
    const int t    = threadIdx.x;
    const int lane = t & 63;
    const int w    = t >> 6;
    const int wm   = w >> 1, wn = w & 1;

    int bid = blockIdx.x;
    int grp = bid / 80, r = bid % 80;
    int mt, nt;
    if (grp < 24) { mt = grp * 8 + (r & 7); nt = r >> 3; }
    else          { mt = 192 + (r & 3);     nt = r >> 2; }   // tail: 4m x 10n
    const int m0 = mt * 128, n0 = nt * 128;
    const int b0 = m0 / SS;
    const int b1 = (m0 + 127) / SS;
    const int bsplit = (b0 + 1) * SS;

    if (t < 128) {
        *(float4*)(wa_s + t * 4) = *(const float4*)(wap + (n0 + t) * 4);
        *(float4*)(sc + t * 4) = (float4){0.f, 0.f, 0.f, 0.f};
        qs[t]       = qatt[(size_t)b0 * DAP + n0 + t];
        qs[128 + t] = qatt[(size_t)b1 * DAP + n0 + t];
    }

    f32x4 acc[4][4];
#pragma unroll
    for (int i = 0; i < 4; ++i)
#pragma unroll
        for (int j = 0; j < 4; ++j) acc[i][j] = (f32x4){0.f, 0.f, 0.f, 0.f};

    const int srow   = lane >> 3;
    const int schunk = (lane & 7) ^ srow;
    const __hip_bfloat16* aG = vt + (size_t)(m0 + w * 32 + srow) * DV + schunk * 8;
    __hip_bfloat16* aL = As + (w * 32) * 64;
    const __hip_bfloat16* bG =
        wt + (size_t)(n0 + wn * 64 + (lane & 15)) * DV + (lane >> 4) * 8;

    for (int k0 = 0; k0 < DV; k0 += 64) {
        __syncthreads();
#pragma unroll
        for (int j = 0; j < 4; ++j)
            async_copy16(aG + (size_t)(j * 8) * DV + k0, aL + j * 8 * 64);
        bf16x8 b[2][4];
#pragma unroll
        for (int ks = 0; ks < 2; ++ks)
#pragma unroll
            for (int ni = 0; ni < 4; ++ni)
                b[ks][ni] = *(const bf16x8*)(bG + (size_t)(ni * 16) * DV + k0 + ks * 32);
        __syncthreads();
#pragma unroll
        for (int ks = 0; ks < 2; ++ks) {
            const int cx = ((ks * 4 + (lane >> 4)) ^ (lane & 7)) * 8;
            bf16x8 a[4];
#pragma unroll
            for (int mi = 0; mi < 4; ++mi)
                a[mi] = *(const bf16x8*)(As + (wm * 64 + mi * 16 + (lane & 15)) * 64 + cx);
#pragma unroll
            for (int mi = 0; mi < 4; ++mi)
#pragma unroll
                for (int ni = 0; ni < 4; ++ni)
                    acc[mi][ni] = __builtin_amdgcn_mfma_f32_16x16x32_bf16(a[mi], b[ks][ni], acc[mi][ni], 0, 0, 0);
        }
    }

    // Epilogue: C/D layout col=lane&15, row=(lane>>4)*4+reg  [m89/m91]
    const int colb_l = wn * 64 + (lane & 15);
    const int colb_g = n0 + colb_l;
    float bvv[4];
    float4 wv[4];
#pragma unroll
    for (int ni = 0; ni < 4; ++ni) {
        bvv[ni] = bvp[colb_g + ni * 16];
        wv[ni]  = *(const float4*)(wa_s + (colb_l + ni * 16) * 4);
    }
#pragma unroll
    for (int mi = 0; mi < 4; ++mi) {
#pragma unroll
        for (int rr = 0; rr < 4; ++rr) {
            int lrow = wm * 64 + mi * 16 + ((lane >> 4) << 2) + rr;   // 0..127
            int row  = m0 + lrow;
            int qoff = (row >= bsplit) ? 128 : 0;
            float p0 = 0.f, p1 = 0.f, p2 = 0.f, p3 = 0.f;
#pragma unroll
            for (int ni = 0; ni < 4; ++ni) {
                float xv = fast_tanh(acc[mi][ni][rr] + bvv[ni]);
                float xa = fast_tanh(xv * qs[qoff + colb_l + ni * 16]);
                p0 += xa * wv[ni].x; p1 += xa * wv[ni].y;
                p2 += xa * wv[ni].z; p3 += xa * wv[ni].w;
            }
#pragma unroll
            for (int mk = 1; mk < 16; mk <<= 1) {
                p0 += __shfl_xor(p0, mk); p1 += __shfl_xor(p1, mk);
                p2 += __shfl_xor(p2, mk); p3 += __shfl_xor(p3, mk);
            }
            if ((lane & 15) == 0) {
                atomicAdd(sc + lrow * 4 + 0, p0);
                atomicAdd(sc + lrow * 4 + 1, p1);
                atomicAdd(sc + lrow * 4 + 2, p2);
                atomicAdd(sc + lrow * 4 + 3, p3);
            }
        }
    }
    __syncthreads();
    if (t < 128)
        *(float4*)(scores_p + ((size_t)nt * MROWS + m0 + t) * 4) = *(float4*)(sc + t * 4);
}

// ---------------------------------------------------------------------------
// K2: sum score partials -> softmax over s -> glimpse pooling -> vattb (bf16).
// ---------------------------------------------------------------------------
__global__ __launch_bounds__(256) void softmax_pool(
    const float* __restrict__ scores_p,
    const __hip_bfloat16* __restrict__ vt,
    __hip_bfloat16* __restrict__ vattb) {
    __shared__ __align__(16) float att[SS * GG];
    const int b = blockIdx.y;
    const int t = threadIdx.x;
    if (t < SS) {
        float4 s = {0.f, 0.f, 0.f, 0.f};
#pragma unroll
        for (int ntile = 0; ntile < NT; ++ntile) {
            float4 p = *(const float4*)(scores_p + ((size_t)ntile * MROWS + b * SS + t) * 4);
            s.x += p.x; s.y += p.y; s.z += p.z; s.w += p.w;
        }
        *(float4*)(att + t * 4) = s;
    }
    __syncthreads();
    {
        const int g = t >> 6;
        const int lane = t & 63;
        float mx = -3.0e38f;
        for (int s = lane; s < SS; s += 64) mx = fmaxf(mx, att[s * 4 + g]);
#pragma unroll
        for (int m = 32; m > 0; m >>= 1) mx = fmaxf(mx, __shfl_xor(mx, m));
        float sum = 0.f;
        for (int s = lane; s < SS; s += 64) sum += __expf(att[s * 4 + g] - mx);
#pragma unroll
        for (int m = 32; m > 0; m >>= 1) sum += __shfl_xor(sum, m);
        float inv = __builtin_amdgcn_rcpf(sum);
        for (int s = lane; s < SS; s += 64) att[s * 4 + g] = __expf(att[s * 4 + g] - mx) * inv;
    }
    __syncthreads();
    const int c = blockIdx.x * 512 + t * 2;
    const __hip_bfloat16* vp = vt + (size_t)b * SS * DV + c;
    float a00 = 0, a01 = 0, a02 = 0, a03 = 0;
    float a10 = 0, a11 = 0, a12 = 0, a13 = 0;
#pragma unroll 4
    for (int s = 0; s < SS; ++s) {
        unsigned u = *(const unsigned*)(vp + (size_t)s * DV);
        float v0 = __uint_as_float(u << 16);
        float v1 = __uint_as_float(u & 0xffff0000u);
        float4 aw = *(const float4*)(att + s * 4);
        a00 += v0 * aw.x; a01 += v0 * aw.y; a02 += v0 * aw.z; a03 += v0 * aw.w;
        a10 += v1 * aw.x; a11 += v1 * aw.y; a12 += v1 * aw.z; a13 += v1 * aw.w;
    }
    __hip_bfloat16* vb = vattb + (size_t)b * GG * DV;
    __hip_bfloat162 h;
    h.x = __float2bfloat16(a00); h.y = __float2bfloat16(a10);
    *(__hip_bfloat162*)(vb + 0 * DV + c) = h;
    h.x = __float2bfloat16(a01); h.y = __float2bfloat16(a11);
    *(__hip_bfloat162*)(vb + 1 * DV + c) = h;
    h.x = __float2bfloat16(a02); h.y = __float2bfloat16(a12);
    *(__hip_bfloat162*)(vb + 2 * DV + c) = h;
    h.x = __float2bfloat16(a03); h.y = __float2bfloat16(a13);
    *(__hip_bfloat162*)(vb + 3 * DV + c) = h;
}

// ---------------------------------------------------------------------------
extern "C" void kernel_launch(void* const* d_in, const int* in_sizes, int n_in,
                              void* d_out, int out_size, void* d_ws, size_t ws_size,
                              hipStream_t stream) {
    const float* input_v = (const float*)d_in[0];
    const float* x_q     = (const float*)d_in[1];
    const float* Wv      = (const float*)d_in[2];
    const float* bv      = (const float*)d_in[3];
    const float* Wq_att  = (const float*)d_in[4];
    const float* bq_att  = (const float*)d_in[5];
    const float* Wa      = (const float*)d_in[6];
    // d_in[7] = ba: constant over softmax axis -> cancels, unused.
    const float* Wf      = (const float*)d_in[8];
    const float* bf_     = (const float*)d_in[9];
    const float* Wqf     = (const float*)d_in[10];
    const float* bqf     = (const float*)d_in[11];
    const float* Wc      = (const float*)d_in[12];
    const float* bc      = (const float*)d_in[13];
    float* out = (float*)d_out;

    char* wsb = (char*)d_ws;
    size_t off = 0;
    auto carve = [&](size_t bytes) -> void* {
        void* p = wsb + off;
        off += (bytes + 255) & ~(size_t)255;
        return p;
    };
    __hip_bfloat16* vt   = (__hip_bfloat16*)carve((size_t)MROWS * DV * 2);  // 102.8 MB
    __hip_bfloat16* wvt  = (__hip_bfloat16*)carve((size_t)DAP * DV * 2);    //   5.2 MB
    __hip_bfloat16* wqT  = (__hip_bfloat16*)carve((size_t)NQ * 2048 * 2);   //  13.6 MB
    __hip_bfloat16* wfT  = (__hip_bfloat16*)carve((size_t)DH * 2048 * 2);   //   8.4 MB
    float* Cp       = (float*)carve((size_t)KS2 * 128 * NQ * 4);            //  27.3 MB
    float* scores_p = (float*)carve((size_t)NT * MROWS * GG * 4);           //   4.0 MB
    float* qatt = (float*)carve((size_t)BB * DAP * 4);
    float* qfus = (float*)carve((size_t)BB * DH * 4);
    float* bvp  = (float*)carve((size_t)DAP * 4);
    float* wap  = (float*)carve((size_t)DAP * GG * 4);
    __hip_bfloat16* xqb   = (__hip_bfloat16*)carve((size_t)BB * DQ * 2);
    __hip_bfloat16* vattb = (__hip_bfloat16*)carve((size_t)BB * GG * DV * 2);
    __hip_bfloat16* xbufb = (__hip_bfloat16*)carve((size_t)BB * DH * 2);
    // wcT aliases wqT: Wc transpose launched AFTER the q-branch GEMM reads wqT.
    __hip_bfloat16* wcT = wqT;    // 12.6 MB <= 13.6 MB
    (void)ws_size; (void)n_in; (void)in_sizes; (void)out_size;

    prep<<<dim3((BB * DQ + 255) / 256), 256, 0, stream>>>(x_q, bv, Wa, xqb, bvp, wap);
    transpose_v<<<dim3(DV / 128, 4, BB), 256, 0, stream>>>(input_v, vt);
    transpose_nk<<<dim3(DAP / 64, 32), 256, 0, stream>>>(Wv, DA, DA, wvt, 0, 0);
    transpose_nk<<<dim3(DAP / 64, 32), 256, 0, stream>>>(Wq_att, DA, DA, wqT, 0, 0);
    transpose_nk<<<dim3(DH / 64, 32), 256, 0, stream>>>(Wqf, DH, DH, wqT + (size_t)DAP * 2048, 0, 0);
    transpose_nk<<<dim3(8, 32, 4), 256, 0, stream>>>(Wf, 512, 512, wfT, (size_t)2048 * 512, 512);

    // merged q-branch GEMM (bf16 MFMA split-K)
    mfma_partial<<<dim3(NQ / 128, KS2), 256, 0, stream>>>(xqb, DQ, wqT, Cp, NQ, 0);
    epilogue_q<<<dim3(NQ / 256, BB), 256, 0, stream>>>(Cp, bq_att, bqf, qatt, qfus);

    // Wc transpose (into wqT's space — safe: stream-serial after q GEMM)
    transpose_nk<<<dim3(NANSP / 64, 32), 256, 0, stream>>>(Wc, NANS, NANS, wcT, 0, 0);

    // big MFMA GEMM with fused score reduction -> scores_p
    big_gemm<<<dim3(24 * 80 + 40), 256, 0, stream>>>(vt, wvt, bvp, qatt, wap, scores_p);

    // softmax over spatial + glimpse pooling -> vattb bf16 [128][4][2048]
    softmax_pool<<<dim3(4, BB), 256, 0, stream>>>(scores_p, vt, vattb);

    // glimpse fusion (bf16 MFMA): xbufb = tanh(tanh(vattb@WfT^T + bf) * qfus)
    mfma_partial<<<dim3(DH / 128, KS2), 256, 0, stream>>>(vattb, GG * DV, wfT, Cp, DH, 1);
    gemm_epilogue<2><<<dim3(DH / 256, BB), 256, 0, stream>>>(Cp, DH, DH, bf_, qfus, xbufb, DH);

    // classifier (bf16 MFMA): out = xbufb @ WcT^T + bc
    mfma_partial<<<dim3(NANSP / 128, KS2), 256, 0, stream>>>(xbufb, DH, wcT, Cp, NANSP, 0);
    gemm_epilogue<0><<<dim3(NANSP / 256, BB), 256, 0, stream>>>(Cp, NANSP, NANS, bc, nullptr, out, NANS);
}